// Round 1
// baseline (774.116 us; speedup 1.0000x reference)
//
#include <hip/hip_runtime.h>
#include <hip/hip_bf16.h>

typedef __attribute__((ext_vector_type(8))) short bf8_t;   // 8 bf16 carried as shorts
typedef __attribute__((ext_vector_type(4))) float f32x4;

#ifndef __has_builtin
#define __has_builtin(x) 0
#endif
#if __has_builtin(__builtin_amdgcn_exp2f)
#define EXP2F(x) __builtin_amdgcn_exp2f(x)
#else
#define EXP2F(x) exp2f(x)
#endif

#define B_ 2
#define SQ_ 2048
#define SK_ 2048
#define H_ 32
#define HKV_ 8
#define D_ 128
#define KVSTRIDE (2 * HKV_ * D_)   /* fp32 elems between consecutive s in kv */
#define QROWSTRIDE (H_ * D_)
#define LOG2E 1.4426950408889634f
#define SCALE 0.08838834764831845f /* 1/sqrt(128) */

__device__ __forceinline__ unsigned short f2bf(float f) {
  unsigned int u = __builtin_bit_cast(unsigned int, f);
  u += 0x7fffu + ((u >> 16) & 1u);   // RNE
  return (unsigned short)(u >> 16);
}
__device__ __forceinline__ float bf2f(unsigned short s) {
  unsigned int u = ((unsigned int)s) << 16;
  return __builtin_bit_cast(float, u);
}

// 4 waves/block, 64 q-rows/block (16 per wave), KV tile = 64.
// LDS: Ksh [64][128] bf16 swizzled (16KB) | Vt [128][64] bf16 swizzled (16KB)
//      | P per-wave [16][64] bf16 swizzled (4 x 2KB)  => 40KB -> 4 blocks/CU.
__global__ void __launch_bounds__(256)
fattn_kernel(const float* __restrict__ q, const float* __restrict__ kv,
             float* __restrict__ out) {
  __shared__ __align__(16) char lds[40960];
  char* Ksh = lds;
  char* Vsh = lds + 16384;
  char* Psh = lds + 32768 + ((threadIdx.x >> 6) << 11);

  const int tid = threadIdx.x;
  const int lane = tid & 63;
  const int w = tid >> 6;
  const int lo = lane & 15;   // col-lane within 16-group
  const int hi = lane >> 4;   // quarter-wave id

  const int bid = blockIdx.x;
  const int qt = bid & 31;          // Sq/64 = 32 tiles
  const int h = (bid >> 5) & 31;    // H = 32
  const int b = bid >> 10;          // B = 2
  const int hkv = h >> 2;           // GQA group 4

  const float* qbase = q + ((size_t)b * SQ_ * H_ + h) * D_;
  const float* kbase = kv + ((size_t)b * SK_ * 2 * HKV_ + hkv) * D_;
  const float* vbase = kv + ((size_t)b * SK_ * 2 * HKV_ + HKV_ + hkv) * D_;

  // ---- Q fragments: 16 rows/wave, pre-scaled, bf16. A-frag: row=lo, k=8*hi+j ----
  const int qrow = qt * 64 + w * 16 + lo;
  const float* qp = qbase + (size_t)qrow * QROWSTRIDE;
  bf8_t qf[4];
#pragma unroll
  for (int kk = 0; kk < 4; ++kk) {
    const int d0 = kk * 32 + hi * 8;
    float4 a = *(const float4*)(qp + d0);
    float4 c = *(const float4*)(qp + d0 + 4);
    bf8_t tq;
    tq[0] = (short)f2bf(a.x * SCALE); tq[1] = (short)f2bf(a.y * SCALE);
    tq[2] = (short)f2bf(a.z * SCALE); tq[3] = (short)f2bf(a.w * SCALE);
    tq[4] = (short)f2bf(c.x * SCALE); tq[5] = (short)f2bf(c.y * SCALE);
    tq[6] = (short)f2bf(c.z * SCALE); tq[7] = (short)f2bf(c.w * SCALE);
    qf[kk] = tq;
  }

  f32x4 o[8];
#pragma unroll
  for (int i = 0; i < 8; ++i) o[i] = (f32x4){0.f, 0.f, 0.f, 0.f};
  float m_r[4] = {-INFINITY, -INFINITY, -INFINITY, -INFINITY};
  float l_r[4] = {0.f, 0.f, 0.f, 0.f};

  for (int t = 0; t < SK_ / 64; ++t) {
    __syncthreads();  // previous tile's LDS reads complete before overwrite

    // ---- stage K tile [64][128] fp32 -> bf16, row-swizzled ----
    {
      const float* k0 = kbase + (size_t)(t * 64) * KVSTRIDE;
#pragma unroll
      for (int i = 0; i < 8; ++i) {
        const int idx4 = tid + i * 256;   // 2048 float4 chunks
        const int row = idx4 >> 5;
        const int c4 = idx4 & 31;
        float4 kk4 = *(const float4*)(k0 + (size_t)row * KVSTRIDE + c4 * 4);
        unsigned int off = (unsigned int)(row * 256 + c4 * 8) ^
                           ((unsigned int)(row & 7) << 4);
        unsigned long long pk =
            (unsigned long long)f2bf(kk4.x) |
            ((unsigned long long)f2bf(kk4.y) << 16) |
            ((unsigned long long)f2bf(kk4.z) << 32) |
            ((unsigned long long)f2bf(kk4.w) << 48);
        *(unsigned long long*)(Ksh + off) = pk;
      }
      // ---- stage V transposed: Vt[d=128][k=64] bf16, d-swizzled.
      // lane = k so transpose-writes hit distinct banks (2-way, free).
      const float* v0 = vbase + (size_t)(t * 64 + lane) * KVSTRIDE;
#pragma unroll
      for (int i = 0; i < 8; ++i) {
        const int d0 = (w * 8 + i) * 4;
        float4 vv = *(const float4*)(v0 + d0);
        float vals[4] = {vv.x, vv.y, vv.z, vv.w};
#pragma unroll
        for (int jj = 0; jj < 4; ++jj) {
          const int d = d0 + jj;
          unsigned int off = (unsigned int)(d * 128 + lane * 2) ^
                             ((unsigned int)(d & 7) << 4);
          *(unsigned short*)(Vsh + off) = f2bf(vals[jj]);
        }
      }
    }
    __syncthreads();

    // ---- S = Q K^T : 4 tiles of 16 cols, K-dim 128 in 4 mfma steps ----
    f32x4 sj[4];
#pragma unroll
    for (int j = 0; j < 4; ++j) {
      f32x4 acc = (f32x4){0.f, 0.f, 0.f, 0.f};
      const int row = j * 16 + lo;
#pragma unroll
      for (int kk = 0; kk < 4; ++kk) {
        unsigned int off = (unsigned int)(row * 256 + kk * 64 + hi * 16) ^
                           ((unsigned int)(row & 7) << 4);
        bf8_t kf = *(const bf8_t*)(Ksh + off);
        acc = __builtin_amdgcn_mfma_f32_16x16x32_bf16(qf[kk], kf, acc, 0, 0, 0);
      }
      sj[j] = acc;
    }

    // ---- online softmax; lane owns rows hi*4+r, cols spread over 16-lane group ----
    float mn[4], corr[4], rs[4];
#pragma unroll
    for (int r = 0; r < 4; ++r) {
      float v = fmaxf(fmaxf(sj[0][r], sj[1][r]), fmaxf(sj[2][r], sj[3][r]));
      v = fmaxf(v, __shfl_xor(v, 1));
      v = fmaxf(v, __shfl_xor(v, 2));
      v = fmaxf(v, __shfl_xor(v, 4));
      v = fmaxf(v, __shfl_xor(v, 8));
      mn[r] = fmaxf(m_r[r], v);
      corr[r] = EXP2F((m_r[r] - mn[r]) * LOG2E);
      m_r[r] = mn[r];
      rs[r] = 0.f;
    }
#pragma unroll
    for (int j = 0; j < 4; ++j) {
#pragma unroll
      for (int r = 0; r < 4; ++r) {
        float p = EXP2F((sj[j][r] - mn[r]) * LOG2E);
        unsigned short pu = f2bf(p);
        rs[r] += bf2f(pu);  // denominator consistent with bf16 numerator
        const int prow = hi * 4 + r;
        const int pcol = j * 16 + lo;
        unsigned int off = (unsigned int)(prow * 128 + pcol * 2) ^
                           ((unsigned int)(prow & 7) << 4);
        *(unsigned short*)(Psh + off) = pu;
      }
    }
#pragma unroll
    for (int r = 0; r < 4; ++r) {
      float v = rs[r];
      v += __shfl_xor(v, 1);
      v += __shfl_xor(v, 2);
      v += __shfl_xor(v, 4);
      v += __shfl_xor(v, 8);
      l_r[r] = l_r[r] * corr[r] + v;
    }
#pragma unroll
    for (int i = 0; i < 8; ++i) {
#pragma unroll
      for (int r = 0; r < 4; ++r) o[i][r] *= corr[r];
    }

    // ---- O += P V : A-frag from Psh, B-frag from Vt (both b128, swizzled) ----
#pragma unroll
    for (int kk = 0; kk < 2; ++kk) {
      unsigned int poff = (unsigned int)(lo * 128 + kk * 64 + hi * 16) ^
                          ((unsigned int)(lo & 7) << 4);
      bf8_t pf = *(const bf8_t*)(Psh + poff);
#pragma unroll
      for (int db = 0; db < 8; ++db) {
        const int d = db * 16 + lo;
        unsigned int voff = (unsigned int)(d * 128 + kk * 64 + hi * 16) ^
                            ((unsigned int)(d & 7) << 4);
        bf8_t vf = *(const bf8_t*)(Vsh + voff);
        o[db] = __builtin_amdgcn_mfma_f32_16x16x32_bf16(pf, vf, o[db], 0, 0, 0);
      }
    }
  }

  // ---- epilogue: normalize and store fp32 ----
  float inv[4];
#pragma unroll
  for (int r = 0; r < 4; ++r) inv[r] = 1.f / l_r[r];
  float* obase = out + ((size_t)b * SQ_ * H_ + h) * D_;
  const int orow0 = qt * 64 + w * 16 + hi * 4;
#pragma unroll
  for (int r = 0; r < 4; ++r) {
    float* op = obase + (size_t)(orow0 + r) * QROWSTRIDE;
#pragma unroll
    for (int db = 0; db < 8; ++db) op[db * 16 + lo] = o[db][r] * inv[r];
  }
}

extern "C" void kernel_launch(void* const* d_in, const int* in_sizes, int n_in,
                              void* d_out, int out_size, void* d_ws, size_t ws_size,
                              hipStream_t stream) {
  (void)in_sizes; (void)n_in; (void)out_size; (void)d_ws; (void)ws_size;
  const float* q = (const float*)d_in[0];
  const float* kv = (const float*)d_in[1];
  float* out = (float*)d_out;
  dim3 grid(B_ * H_ * (SQ_ / 64));  // 2048 blocks; consecutive bids share KV (L2 locality)
  dim3 block(256);
  hipLaunchKernelGGL(fattn_kernel, grid, block, 0, stream, q, kv, out);
}

// Round 2
// 342.160 us; speedup vs baseline: 2.2624x; 2.2624x over previous
//
#include <hip/hip_runtime.h>
#include <hip/hip_bf16.h>

typedef __attribute__((ext_vector_type(8))) short bf8_t;    // 8 bf16 as shorts
typedef __attribute__((ext_vector_type(16))) float f32x16;

#ifndef __has_builtin
#define __has_builtin(x) 0
#endif
#if __has_builtin(__builtin_amdgcn_exp2f)
#define EXP2F(x) __builtin_amdgcn_exp2f(x)
#else
#define EXP2F(x) exp2f(x)
#endif

#define B_ 2
#define SQ_ 2048
#define SK_ 2048
#define H_ 32
#define HKV_ 8
#define D_ 128
#define KVSTRIDE (2 * HKV_ * D_)
#define QSTRIDE (H_ * D_)
#define NT (SK_ / 64)
// softmax scale folded with log2(e): P = exp2(s - m) with s already in log2 units
#define SCLOG (0.08838834764831845f * 1.4426950408889634f)

__device__ __forceinline__ unsigned short f2bf(float f) {
  unsigned int u = __builtin_bit_cast(unsigned int, f);
  u += 0x7fffu + ((u >> 16) & 1u);  // RNE
  return (unsigned short)(u >> 16);
}
__device__ __forceinline__ unsigned int pk2(float a, float b) {
  return (unsigned int)f2bf(a) | ((unsigned int)f2bf(b) << 16);
}

// 8 waves x 32 q-rows = 256 q-rows/block. KVBLK = 64. mfma 32x32x16 bf16.
// Swapped QK^T and PV: lane&31 == q-row for S, m, l, O^T columns.
// LDS: Ksh [64][128] bf16 row-swizzled (16KB) | Vt [128][64] bf16 d-swizzled,
// kv-column-PERMUTED so PV B-frag = lane's own 8 consecutive S regs (16KB).
__global__ void __launch_bounds__(512, 2)
fattn2(const float* __restrict__ q, const float* __restrict__ kv,
       float* __restrict__ out) {
  __shared__ __align__(16) char lds[32768];
  char* Ksh = lds;
  char* Vsh = lds + 16384;

  const int tid = threadIdx.x;
  const int lane = tid & 63;
  const int w = tid >> 6;
  const int ql = lane & 31;  // q-row within warp tile
  const int hi = lane >> 5;  // half-wave id

  const int bid = blockIdx.x;
  const int qt = bid & 7;          // 8 q-tiles of 256 rows
  const int h = (bid >> 3) & 31;   // H
  const int b = bid >> 8;          // B
  const int hkv = h >> 2;

  const float* qbase = q + ((size_t)b * SQ_ * H_ + h) * D_;
  const float* kbase = kv + ((size_t)b * SK_ * 2 * HKV_ + hkv) * D_;
  const float* vbase = kv + ((size_t)b * SK_ * 2 * HKV_ + HKV_ + hkv) * D_;

  // ---- Q fragments in registers: B-frag for swapped QK^T.
  // lane holds Q[q = ql][d = step*16 + hi*8 + j] * SCALE*log2e, 8 steps.
  const int qrow = qt * 256 + w * 32 + ql;
  const float* qp = qbase + (size_t)qrow * QSTRIDE;
  bf8_t qf[8];
#pragma unroll
  for (int step = 0; step < 8; ++step) {
    const int d0 = step * 16 + hi * 8;
    float4 a = *(const float4*)(qp + d0);
    float4 c = *(const float4*)(qp + d0 + 4);
    bf8_t tq;
    tq[0] = (short)f2bf(a.x * SCLOG); tq[1] = (short)f2bf(a.y * SCLOG);
    tq[2] = (short)f2bf(a.z * SCLOG); tq[3] = (short)f2bf(a.w * SCLOG);
    tq[4] = (short)f2bf(c.x * SCLOG); tq[5] = (short)f2bf(c.y * SCLOG);
    tq[6] = (short)f2bf(c.z * SCLOG); tq[7] = (short)f2bf(c.w * SCLOG);
    qf[step] = tq;
  }

  // ---- kv-column permutation for zero-shuffle PV.
  // S^T C-layout row (kv) = (r&3)+8*(r>>2)+4*hi+32*b ; B-frag slot (ks,hi,j)
  // consumes p[ks>>1][8*(ks&1)+j]  =>  kv -> kcol = 16*ks + 8*hi + j.
  const int vkv = lane;  // staging: this lane stages kv-row = lane
  int kcol;
  {
    const int wv = vkv & 31, bb = vkv >> 5;
    const int T_ = (wv >> 2) & 1;
    const int rr = (wv & 3) + ((wv >> 3) << 2);
    kcol = (((bb << 1) + (rr >> 3)) << 4) + (T_ << 3) + (rr & 7);
  }

  // ---- accumulators ----
  f32x16 o[4];  // O^T, 4 d-blocks of 32; col = ql
  f32x16 st[2];
#pragma unroll
  for (int i = 0; i < 4; ++i)
#pragma unroll
    for (int r = 0; r < 16; ++r) o[i][r] = 0.f;
  float m = -INFINITY, l = 0.f;

  // ---- staging registers (T14: loads issued a tile early) ----
  float4 krg[4], vrg[4];
  const int krow0 = tid >> 5;        // + 16*i
  const int kc4 = tid & 31;          // float4 column chunk
  auto load_tiles = [&](int T) {
    const float* kp0 = kbase + ((size_t)T * 64 + krow0) * KVSTRIDE + kc4 * 4;
#pragma unroll
    for (int i = 0; i < 4; ++i)
      krg[i] = *(const float4*)(kp0 + (size_t)(16 * i) * KVSTRIDE);
    const float* vp0 = vbase + ((size_t)T * 64 + vkv) * KVSTRIDE + w * 16;
#pragma unroll
    for (int i = 0; i < 4; ++i) vrg[i] = *(const float4*)(vp0 + 4 * i);
  };
  load_tiles(0);

  for (int t = 0; t < NT; ++t) {
    __syncthreads();  // previous tile's LDS reads complete

    // ---- write staged regs -> LDS ----
#pragma unroll
    for (int i = 0; i < 4; ++i) {  // K: [row][d] bf16, row-swizzled, b64
      const int row = krow0 + 16 * i;
      unsigned int off = (unsigned int)(row * 256 + kc4 * 8) ^
                         ((unsigned int)(row & 7) << 4);
      float4 kk = krg[i];
      unsigned long long pkw =
          (unsigned long long)f2bf(kk.x) |
          ((unsigned long long)f2bf(kk.y) << 16) |
          ((unsigned long long)f2bf(kk.z) << 32) |
          ((unsigned long long)f2bf(kk.w) << 48);
      *(unsigned long long*)(Ksh + off) = pkw;
    }
#pragma unroll
    for (int i = 0; i < 4; ++i) {  // V^T: [d][kcol] bf16, d-swizzled, b16
      float4 vv = vrg[i];
      float vals[4] = {vv.x, vv.y, vv.z, vv.w};
#pragma unroll
      for (int jj = 0; jj < 4; ++jj) {
        const int dj = w * 16 + i * 4 + jj;
        unsigned int off = (unsigned int)(dj * 128 + kcol * 2) ^
                           ((unsigned int)(dj & 7) << 4);
        *(unsigned short*)(Vsh + off) = f2bf(vals[jj]);
      }
    }
    __syncthreads();

    if (t + 1 < NT) load_tiles(t + 1);  // T14: hide HBM under compute

    // ---- S^T = K Q^T : 2 kv-blocks x 8 d-steps ----
#pragma unroll
    for (int r = 0; r < 16; ++r) { st[0][r] = 0.f; st[1][r] = 0.f; }
#pragma unroll
    for (int step = 0; step < 8; ++step) {
#pragma unroll
      for (int bb2 = 0; bb2 < 2; ++bb2) {
        const int row = bb2 * 32 + ql;
        unsigned int off = (unsigned int)(row * 256 + (step * 16 + hi * 8) * 2) ^
                           ((unsigned int)(row & 7) << 4);
        bf8_t kf = *(const bf8_t*)(Ksh + off);
        st[bb2] = __builtin_amdgcn_mfma_f32_32x32x16_bf16(kf, qf[step], st[bb2], 0, 0, 0);
      }
    }

    // ---- in-register online softmax (lane owns q-row ql; partner = lane^32) ----
    float mx = st[0][0];
#pragma unroll
    for (int r = 1; r < 16; ++r) mx = fmaxf(mx, st[0][r]);
#pragma unroll
    for (int r = 0; r < 16; ++r) mx = fmaxf(mx, st[1][r]);
    mx = fmaxf(mx, __shfl_xor(mx, 32));

    const int sk = __all(mx <= m + 8.0f);  // T13 defer-max (log2 domain)
    float mn, corr;
    if (sk) { mn = m; corr = 1.f; }
    else { mn = fmaxf(m, mx); corr = EXP2F(m - mn); m = mn; }

    float ls = 0.f;
#pragma unroll
    for (int bb2 = 0; bb2 < 2; ++bb2)
#pragma unroll
      for (int r = 0; r < 16; ++r) {
        float pv = EXP2F(st[bb2][r] - mn);
        st[bb2][r] = pv;
        ls += pv;
      }
    ls += __shfl_xor(ls, 32);
    l = l * corr + ls;
    if (!sk) {
#pragma unroll
      for (int i = 0; i < 4; ++i)
#pragma unroll
        for (int r = 0; r < 16; ++r) o[i][r] *= corr;
    }

    // ---- O^T += V^T P^T : zero-shuffle B-frag from own regs ----
#pragma unroll
    for (int ks = 0; ks < 4; ++ks) {
      const int b_ = ks >> 1, rb = (ks & 1) * 8;
      union { unsigned int u[4]; bf8_t v; } pw;
      pw.u[0] = pk2(st[b_][rb + 0], st[b_][rb + 1]);
      pw.u[1] = pk2(st[b_][rb + 2], st[b_][rb + 3]);
      pw.u[2] = pk2(st[b_][rb + 4], st[b_][rb + 5]);
      pw.u[3] = pk2(st[b_][rb + 6], st[b_][rb + 7]);
      const bf8_t pf = pw.v;
#pragma unroll
      for (int dblk = 0; dblk < 4; ++dblk) {
        const int d = dblk * 32 + ql;
        unsigned int off = (unsigned int)(d * 128 + (ks * 16 + hi * 8) * 2) ^
                           ((unsigned int)(d & 7) << 4);
        bf8_t vf = *(const bf8_t*)(Vsh + off);
        o[dblk] = __builtin_amdgcn_mfma_f32_32x32x16_bf16(vf, pf, o[dblk], 0, 0, 0);
      }
    }
  }

  // ---- epilogue: normalize, transpose O^T via warp-private LDS, store ----
  __syncthreads();  // all warps done with K/V staging buffers
  const float invl = 1.f / l;
  float* ep = (float*)(lds + (w << 12));  // 4KB per warp: [32 d][32 q] xor-swz
#pragma unroll
  for (int dblk = 0; dblk < 4; ++dblk) {
#pragma unroll
    for (int r = 0; r < 16; ++r) {
      const int dd = (r & 3) + 8 * (r >> 2) + 4 * hi;
      ep[dd * 32 + (ql ^ dd)] = o[dblk][r] * invl;
    }
    // same-wave, same-object LDS ordering: compiler inserts lgkmcnt
#pragma unroll
    for (int p = 0; p < 16; ++p) {
      const int idx = p * 64 + lane;
      const int q2 = idx >> 5, dd2 = idx & 31;
      float v = ep[dd2 * 32 + (q2 ^ dd2)];
      out[((size_t)(b * SQ_ + qt * 256 + w * 32 + q2) * H_ + h) * D_ +
          dblk * 32 + dd2] = v;
    }
  }
}

extern "C" void kernel_launch(void* const* d_in, const int* in_sizes, int n_in,
                              void* d_out, int out_size, void* d_ws, size_t ws_size,
                              hipStream_t stream) {
  (void)in_sizes; (void)n_in; (void)out_size; (void)d_ws; (void)ws_size;
  const float* q = (const float*)d_in[0];
  const float* kv = (const float*)d_in[1];
  float* out = (float*)d_out;
  dim3 grid(B_ * H_ * 8);  // 512 blocks; qt fastest -> KV shared by neighbors
  dim3 block(512);
  hipLaunchKernelGGL(fattn2, grid, block, 0, stream, q, kv, out);
}

// Round 5
// 289.065 us; speedup vs baseline: 2.6780x; 1.1837x over previous
//
#include <hip/hip_runtime.h>
#include <hip/hip_bf16.h>

typedef __attribute__((ext_vector_type(8))) short bf8_t;    // 8 bf16 as shorts
typedef __attribute__((ext_vector_type(16))) float f32x16;

#ifndef __has_builtin
#define __has_builtin(x) 0
#endif
#if __has_builtin(__builtin_amdgcn_exp2f)
#define EXP2F(x) __builtin_amdgcn_exp2f(x)
#else
#define EXP2F(x) exp2f(x)
#endif

#define B_ 2
#define SQ_ 2048
#define SK_ 2048
#define H_ 32
#define HKV_ 8
#define D_ 128
#define KVSTRIDE (2 * HKV_ * D_)
#define QSTRIDE (H_ * D_)
#define NT (SK_ / 64)
// softmax scale folded with log2(e); all softmax math in log2 domain
#define SCLOG 0.12754984679800714f

// fp32 -> packed bf16 pair; compiles to v_cvt_pk_bf16_f32 (T12/m240)
__device__ __forceinline__ unsigned int cvtpk(float a, float b) {
  union { __hip_bfloat162 h; unsigned int u; } c;
  c.h = __float22bfloat162_rn(make_float2(a, b));
  return c.u;
}

// 8 waves x 32 q-rows = 256 q-rows/block. KVBLK=64. mfma 32x32x16 bf16.
// Swapped QK^T and PV; zero-shuffle PV via kv-column-permuted V^T layout.
// LDS: 2 x { K [64 rows][256B] swz ^(r&15)<<4  |  Vt [64 rows][256B]:
//   row r holds d=r (bytes 0..127) and d=r+64 (bytes 128..255), col=kcol,
//   same swizzle }  = 2 x 32KB. One barrier per tile (double-buffered).
__global__ void __launch_bounds__(512, 1)
fattn3(const float* __restrict__ q, const float* __restrict__ kv,
       float* __restrict__ out) {
  __shared__ __align__(16) char lds[65536];

  const int tid = threadIdx.x;
  const int lane = tid & 63;
  const int w = tid >> 6;
  const int ql = lane & 31;  // q-row within warp tile
  const int hi = lane >> 5;  // half-wave id

  const int bid = blockIdx.x;
  const int qt = bid & 7;
  const int h = (bid >> 3) & 31;
  const int b = bid >> 8;
  const int hkv = h >> 2;

  const float* qbase = q + ((size_t)b * SQ_ * H_ + h) * D_;
  const float* kbase = kv + ((size_t)b * SK_ * 2 * HKV_ + hkv) * D_;
  const float* vbase = kv + ((size_t)b * SK_ * 2 * HKV_ + HKV_ + hkv) * D_;

  // ---- Q fragments: lane ql holds Q[ql][s*16 + hi*8 + j] * SCLOG ----
  const int qrow = qt * 256 + w * 32 + ql;
  const float* qp = qbase + (size_t)qrow * QSTRIDE;
  bf8_t qf[8];
#pragma unroll
  for (int s = 0; s < 8; ++s) {
    const int d0 = s * 16 + hi * 8;
    float4 a = *(const float4*)(qp + d0);
    float4 c = *(const float4*)(qp + d0 + 4);
    union { unsigned int u[4]; bf8_t v; } t_;
    t_.u[0] = cvtpk(a.x * SCLOG, a.y * SCLOG);
    t_.u[1] = cvtpk(a.z * SCLOG, a.w * SCLOG);
    t_.u[2] = cvtpk(c.x * SCLOG, c.y * SCLOG);
    t_.u[3] = cvtpk(c.z * SCLOG, c.w * SCLOG);
    qf[s] = t_.v;
  }

  // ---- staging geometry ----
  const int krow = tid >> 5;    // K rows krow + 16*i, coalesced 16B chunks
  const int kc4 = tid & 31;
  const int p = tid & 31;       // V kv-pair (2p, 2p+1)
  const int dchunk = tid >> 5;  // V d-range dchunk*8 .. +7
  int kcol2;                    // kcol(2p); kcol(2p+1) = kcol2+1
  {
    const int vkv = 2 * p;
    const int wv = vkv & 31, bb = vkv >> 5;
    const int T_ = (wv >> 2) & 1;
    const int rr = (wv & 3) + ((wv >> 3) << 2);
    kcol2 = (((bb << 1) + (rr >> 3)) << 4) + (T_ << 3) + (rr & 7);
  }

  float4 krg[4], vrg[4];
  auto load_tiles = [&](int T) {
    const float* kp0 = kbase + ((size_t)T * 64 + krow) * KVSTRIDE + kc4 * 4;
#pragma unroll
    for (int i = 0; i < 4; ++i)
      krg[i] = *(const float4*)(kp0 + (size_t)(16 * i) * KVSTRIDE);
    const float* vp0 = vbase + ((size_t)T * 64 + 2 * p) * KVSTRIDE + dchunk * 8;
    vrg[0] = *(const float4*)(vp0);
    vrg[1] = *(const float4*)(vp0 + 4);
    vrg[2] = *(const float4*)(vp0 + KVSTRIDE);
    vrg[3] = *(const float4*)(vp0 + KVSTRIDE + 4);
  };

  auto store_tiles = [&](char* Ksh, char* Vsh) {
#pragma unroll
    for (int i = 0; i < 4; ++i) {  // K: b64, conflict-free (32 lanes / 256B)
      const int row = krow + 16 * i;
      unsigned int off = ((unsigned int)(row * 256 + kc4 * 8)) ^
                         ((unsigned int)(row & 15) << 4);
      union { unsigned int u[2]; unsigned long long ll; } t_;
      t_.u[0] = cvtpk(krg[i].x, krg[i].y);
      t_.u[1] = cvtpk(krg[i].z, krg[i].w);
      *(unsigned long long*)(Ksh + off) = t_.ll;
    }
    // V: pack (kv=2p, kv=2p+1) -> b32 at adjacent kcol; 32 lanes = 32 banks
    const float va[8] = {vrg[0].x, vrg[0].y, vrg[0].z, vrg[0].w,
                         vrg[1].x, vrg[1].y, vrg[1].z, vrg[1].w};
    const float vb[8] = {vrg[2].x, vrg[2].y, vrg[2].z, vrg[2].w,
                         vrg[3].x, vrg[3].y, vrg[3].z, vrg[3].w};
#pragma unroll
    for (int jj = 0; jj < 8; ++jj) {
      const int d = dchunk * 8 + jj;
      const int r = d & 63;
      unsigned int off =
          ((unsigned int)(r * 256 + (d >> 6) * 128 + kcol2 * 2)) ^
          ((unsigned int)(r & 15) << 4);
      *(unsigned int*)(Vsh + off) = cvtpk(va[jj], vb[jj]);
    }
  };

  // ---- accumulators ----
  f32x16 o[4];
  f32x16 st[2];
#pragma unroll
  for (int i = 0; i < 4; ++i)
#pragma unroll
    for (int r = 0; r < 16; ++r) o[i][r] = 0.f;
  float m = -INFINITY, l = 0.f;

  // ---- prologue: fill buf0, prefetch tile 1 ----
  load_tiles(0);
  store_tiles(lds, lds + 16384);
  load_tiles(1);
  __syncthreads();

  for (int t = 0; t < NT; ++t) {
    char* Kc = lds + ((t & 1) << 15);
    char* Vc = Kc + 16384;

    // ---- S^T = K Q^T ----
#pragma unroll
    for (int r = 0; r < 16; ++r) { st[0][r] = 0.f; st[1][r] = 0.f; }
    __builtin_amdgcn_s_setprio(1);
#pragma unroll
    for (int s = 0; s < 8; ++s) {
#pragma unroll
      for (int bb2 = 0; bb2 < 2; ++bb2) {
        const int row = bb2 * 32 + ql;
        unsigned int off = ((unsigned int)(row * 256 + s * 32 + hi * 16)) ^
                           ((unsigned int)(row & 15) << 4);
        bf8_t kf = *(const bf8_t*)(Kc + off);
        st[bb2] =
            __builtin_amdgcn_mfma_f32_32x32x16_bf16(kf, qf[s], st[bb2], 0, 0, 0);
      }
    }
    __builtin_amdgcn_s_setprio(0);

    // ---- online softmax (lane-local; partner = lane^32) ----
    float mv[8];
#pragma unroll
    for (int r = 0; r < 8; ++r)
      mv[r] = fmaxf(fmaxf(st[0][r], st[0][r + 8]),
                    fmaxf(st[1][r], st[1][r + 8]));
    float mx = fmaxf(fmaxf(fmaxf(mv[0], mv[1]), fmaxf(mv[2], mv[3])),
                     fmaxf(fmaxf(mv[4], mv[5]), fmaxf(mv[6], mv[7])));
    mx = fmaxf(mx, __shfl_xor(mx, 32));

    const int sk = __all(mx <= m + 8.0f);  // T13 defer-max (log2 domain)
    float mn, corr;
    if (sk) { mn = m; corr = 1.f; }
    else { mn = fmaxf(m, mx); corr = EXP2F(m - mn); m = mn; }

    float ls = 0.f;
#pragma unroll
    for (int bb2 = 0; bb2 < 2; ++bb2)
#pragma unroll
      for (int r = 0; r < 16; ++r) {
        float pv = EXP2F(st[bb2][r] - mn);
        st[bb2][r] = pv;
        ls += pv;
      }
    ls += __shfl_xor(ls, 32);
    l = l * corr + ls;
    if (!sk) {
#pragma unroll
      for (int i = 0; i < 4; ++i)
#pragma unroll
        for (int r = 0; r < 16; ++r) o[i][r] *= corr;
    }

    // ---- stage next tile into the other buffer (drain hides under PV) ----
    if (t + 1 < NT) {
      char* Kn = lds + (((t + 1) & 1) << 15);
      store_tiles(Kn, Kn + 16384);
      if (t + 2 < NT) load_tiles(t + 2);  // T14: HBM hides under next compute
    }

    // ---- O^T += V^T P^T : B-frag = lane's own 8 consecutive P regs ----
    __builtin_amdgcn_s_setprio(1);
#pragma unroll
    for (int ks = 0; ks < 4; ++ks) {
      const int b_ = ks >> 1, rb = (ks & 1) * 8;
      union { unsigned int u[4]; bf8_t v; } pw;
      pw.u[0] = cvtpk(st[b_][rb + 0], st[b_][rb + 1]);
      pw.u[1] = cvtpk(st[b_][rb + 2], st[b_][rb + 3]);
      pw.u[2] = cvtpk(st[b_][rb + 4], st[b_][rb + 5]);
      pw.u[3] = cvtpk(st[b_][rb + 6], st[b_][rb + 7]);
      const bf8_t pf = pw.v;
#pragma unroll
      for (int dblk = 0; dblk < 4; ++dblk) {
        const int d = dblk * 32 + ql;
        const int r = d & 63;
        unsigned int off =
            ((unsigned int)(r * 256 + (d >> 6) * 128 + ks * 32 + hi * 16)) ^
            ((unsigned int)(r & 15) << 4);
        bf8_t vf = *(const bf8_t*)(Vc + off);
        o[dblk] = __builtin_amdgcn_mfma_f32_32x32x16_bf16(vf, pf, o[dblk], 0, 0, 0);
      }
    }
    __builtin_amdgcn_s_setprio(0);

    __syncthreads();  // single barrier per tile
  }

  // ---- epilogue: normalize, transpose O^T via warp-private LDS, store ----
  const float invl = 1.f / l;
  float* ep = (float*)(lds + (w << 12));  // 4KB per warp, xor-swz [32 d][32 q]
#pragma unroll
  for (int dblk = 0; dblk < 4; ++dblk) {
#pragma unroll
    for (int r = 0; r < 16; ++r) {
      const int dd = (r & 3) + 8 * (r >> 2) + 4 * hi;
      ep[dd * 32 + (ql ^ dd)] = o[dblk][r] * invl;
    }
#pragma unroll
    for (int pp = 0; pp < 16; ++pp) {
      const int idx = pp * 64 + lane;
      const int q2 = idx >> 5, dd2 = idx & 31;
      float v = ep[dd2 * 32 + (q2 ^ dd2)];
      out[((size_t)(b * SQ_ + qt * 256 + w * 32 + q2) * H_ + h) * D_ +
          dblk * 32 + dd2] = v;
    }
  }
}

extern "C" void kernel_launch(void* const* d_in, const int* in_sizes, int n_in,
                              void* d_out, int out_size, void* d_ws, size_t ws_size,
                              hipStream_t stream) {
  (void)in_sizes; (void)n_in; (void)out_size; (void)d_ws; (void)ws_size;
  const float* q = (const float*)d_in[0];
  const float* kv = (const float*)d_in[1];
  float* out = (float*)d_out;
  dim3 grid(B_ * H_ * 8);  // qt fastest -> neighboring blocks share KV in L2
  dim3 block(512);
  hipLaunchKernelGGL(fattn3, grid, block, 0, stream, q, kv, out);
}